// Round 8
// baseline (669.421 us; speedup 1.0000x reference)
//
#include <hip/hip_runtime.h>

// LSTMP via MFMA, fp32 I/O, f16 compute, fp32 accumulate.
// B=4096, T=512, IN=4, HID=64, PROJ=52. Grid 256 x 512thr, 16 batch/block.
//
// Round-20: PRODUCER/CONSUMER WAVE SPECIALIZATION (no barriers in t-loop).
// Evidence: R13 (1 barrier) 1090 cyc/step; R16/R19 reorderings null/worse;
// R15 sibling blocks null. Common cause: all waves run the SAME role at the
// same time -> trans pipe idles during read/MFMA windows and vice versa.
// Fix: waves 0-3 = producers (gates = xb + M@d via MFMA, per-cell packed:
// lane f32x4 = [i,f,g,o] of one cell -> handoff = 1 ds_write_b128);
// waves 4-7 = consumers (trans + cell update + f16 d write). Wave i and
// i+4 share a SIMD -> each SIMD has one MFMA wave + one trans wave live.
// Batches split into 2 independent groups A(b0-7)/B(b8-15) -> half-steps
// u = 2t+g; pipeline P(u+1) || C(u). Sync via monotonic LDS flags:
//   P(u): wait min4(dflag) >= u-1   (d_g(t-1) ready AND gates_g(t-2) read)
//   C(u): wait min4(gflag) >= u+1   (gates_g(t) ready AND d_g(t-1) read)
// writer: data ds_writes -> s_waitcnt lgkmcnt(0) -> flag (lane 0).
// lgkmcnt(0) also drains reads => flag n+1 proves reads of step n done =>
// single-buffer d per group and single-buffer gates per group are safe.
// Bounded spin (1M iters + s_sleep) => worst case = wrong answer, not hang.
// Per-output graph (xb seed, M0, M1; scales; f32 gates via LDS; f16 RTNE d)
// identical to R16 (verified) -> absmax exactly 9.765625e-4.
//   gates = (Whh@Whr)@d + [Wih|b]@[x;1]   (M precomputed, fp32)
// x staged to LDS f16 once; log2e folded (i,f,o xL; g x2L; c' = 2L*c);
// h only in epilogue (Whr@d_T, producers, after dflag>=1024).

#define T_STEPS 512
#define HID 64
#define NPROJ 52
#define NBATCH 16
#define ROWB 136
#define DOFF  65536                  // d buffer offset in lds[]
#define GOFF  (65536 + 2176)         // gates buffers offset (16B aligned)
#define GSZ   8192                   // per-group gates: 64 hid x 8 batch x 16B
#define LOG2E 1.44269504088896340736f

typedef _Float16 half8 __attribute__((ext_vector_type(8)));
typedef float f32x4 __attribute__((ext_vector_type(4)));
typedef unsigned long long ull;

__device__ __forceinline__ float exp2_f(float x) {
#if __has_builtin(__builtin_amdgcn_exp2f)
    return __builtin_amdgcn_exp2f(x);
#else
    return exp2f(x);
#endif
}
__device__ __forceinline__ float rcp_f(float x) {
    return __builtin_amdgcn_rcpf(x);
}

// Wait until all four flags >= need. Wave-uniform (all lanes read the same
// LDS words). Bounded: a protocol bug fails verification instead of hanging.
__device__ __forceinline__ void poll4(volatile int* f, int need) {
    if (f[0] >= need && f[1] >= need && f[2] >= need && f[3] >= need) {
        asm volatile("" ::: "memory");
        return;
    }
    int it = 0;
    while (!(f[0] >= need && f[1] >= need && f[2] >= need && f[3] >= need)) {
        __builtin_amdgcn_s_sleep(1);
        if (++it > (1 << 20)) break;   // safety valve
    }
    asm volatile("" ::: "memory");
}

__global__ __launch_bounds__(512, 2)
void lstmp_kernel(const float* __restrict__ x,      // [4096][512][4]
                  const float* __restrict__ Wih,    // [256][4]
                  const float* __restrict__ Whh,    // [256][52]
                  const float* __restrict__ bih,    // [256]
                  const float* __restrict__ bhh,    // [256]
                  const float* __restrict__ Whr,    // [52][64]
                  float* __restrict__ out)          // [4096][52]
{
    __shared__ char lds[GOFF + 2 * GSZ];   // x 64K | d 2176 | gates 2x8K
    __shared__ int flags[8];               // [0..3] gflag, [4..7] dflag
    char* xl = lds;
    char* dl = lds + DOFF;                 // d[16 batch][136B]; rows 0-7 = grp A

    const int tid  = threadIdx.x;
    const int lane = tid & 63;
    const int wave = tid >> 6;             // 0-3 producers, 4-7 consumers
    const int quad = lane >> 4;
    const int col  = lane & 15;

    if (tid < 8) flags[tid] = 0;
    {   // zero d buffer (d(-1) = 0 for both groups)
        unsigned* p = (unsigned*)dl;
        for (int i = tid; i < 2176 / 4; i += 512) p[i] = 0u;
    }

    // ---- stage x -> LDS as f16 (one-time; coalesced global reads) ----
    {
        const float4* xg = (const float4*)x + (size_t)blockIdx.x * NBATCH * T_STEPS;
        for (int i = tid; i < NBATCH * T_STEPS; i += 512) {
            const int b = i >> 9;          // global layout is b-major
            const int t = i & (T_STEPS - 1);
            const float4 v = xg[i];
            union { _Float16 h[4]; ull q; } u;
            u.h[0] = (_Float16)v.x; u.h[1] = (_Float16)v.y;
            u.h[2] = (_Float16)v.z; u.h[3] = (_Float16)v.w;
            *(ull*)(xl + t * 128 + b * 8) = u.q;
        }
    }

    __syncthreads();   // staging + zeros + flag init visible; ONLY block barrier

    volatile int* vg = flags;       // gflag[p]
    volatile int* vd = flags + 4;   // dflag[c]

    if (wave < 4) {
        // ===================== PRODUCER (hid slice [16w,16w+16)) ==========
        const int w    = wave;
        const int gate = col & 3;
        const int hloc = col >> 2;
        int rowT[4];
#pragma unroll
        for (int j = 0; j < 4; ++j) rowT[j] = gate * HID + w * 16 + 4 * j + hloc;

        // one-time: M = Whh @ Whr for the 4 packed rows (fp32)
        float macc[4][16];
#pragma unroll
        for (int j = 0; j < 4; ++j)
#pragma unroll
            for (int kk = 0; kk < 16; ++kk) macc[j][kk] = 0.0f;
        for (int p = 0; p < NPROJ; ++p) {
            float wv[4];
#pragma unroll
            for (int j = 0; j < 4; ++j) wv[j] = Whh[rowT[j] * NPROJ + p];
            const float* wr = Whr + p * HID + quad * 8;
            const float4 r0 = *(const float4*)(wr);
            const float4 r1 = *(const float4*)(wr + 4);
            const float4 r2 = *(const float4*)(wr + 32);
            const float4 r3 = *(const float4*)(wr + 36);
            const float rk[16] = {r0.x, r0.y, r0.z, r0.w, r1.x, r1.y, r1.z, r1.w,
                                  r2.x, r2.y, r2.z, r2.w, r3.x, r3.y, r3.z, r3.w};
#pragma unroll
            for (int j = 0; j < 4; ++j)
#pragma unroll
                for (int kk = 0; kk < 16; ++kk)
                    macc[j][kk] = fmaf(wv[j], rk[kk], macc[j][kk]);
        }
        const float sc = (gate == 2) ? (2.0f * LOG2E) : LOG2E;   // g rows x2L
        half8 aM[4][2], aXB[4];
#pragma unroll
        for (int j = 0; j < 4; ++j) {
#pragma unroll
            for (int ch = 0; ch < 2; ++ch)
#pragma unroll
                for (int jj = 0; jj < 8; ++jj)
                    aM[j][ch][jj] = (_Float16)(macc[j][ch * 8 + jj] * sc);
#pragma unroll
            for (int jj = 0; jj < 8; ++jj) {
                const int k = quad * 8 + jj;
                float v = 0.0f;
                if (k < 4)       v = Wih[rowT[j] * 4 + k];
                else if (k == 4) v = bih[rowT[j]] + bhh[rowT[j]];
                aXB[j][jj] = (_Float16)(v * sc);
            }
        }

        const int bloc = col & 7;
        const f32x4 z = {0.f, 0.f, 0.f, 0.f};

#pragma unroll 1
        for (int u = 0; u < 2 * T_STEPS; ++u) {
            const int g = u & 1, t = u >> 1;
            poll4(vd, u - 1);   // d_g(t-1) written; gates_g(t-2) fully read

            // reads: x(t) for batch 8g+bloc (quad0), d_g(t-1) B-frags
            union { ull q; _Float16 h[4]; } xu;
            xu.q = (quad == 0)
                 ? *(const ull*)(xl + t * 128 + (g * 8 + bloc) * 8) : 0ull;
            const char* p0 = dl + (g * 8 + bloc) * ROWB + quad * 16;
            union { ull q[2]; half8 h; } u0, u1;
            u0.q[0] = *(const ull*)(p0);      u0.q[1] = *(const ull*)(p0 + 8);
            u1.q[0] = *(const ull*)(p0 + 64); u1.q[1] = *(const ull*)(p0 + 72);

            half8 bx;
#pragma unroll
            for (int jj = 0; jj < 8; ++jj) bx[jj] = (_Float16)0.0f;
            if (quad == 0) {
                bx[0] = xu.h[0]; bx[1] = xu.h[1]; bx[2] = xu.h[2]; bx[3] = xu.h[3];
                bx[4] = (_Float16)1.0f;
            }

            // accumulate order per output: xb, M0(bd0), M1(bd1) — as R16
            f32x4 T0 = __builtin_amdgcn_mfma_f32_16x16x32_f16(aXB[0], bx, z, 0, 0, 0);
            f32x4 T1 = __builtin_amdgcn_mfma_f32_16x16x32_f16(aXB[1], bx, z, 0, 0, 0);
            f32x4 T2 = __builtin_amdgcn_mfma_f32_16x16x32_f16(aXB[2], bx, z, 0, 0, 0);
            f32x4 T3 = __builtin_amdgcn_mfma_f32_16x16x32_f16(aXB[3], bx, z, 0, 0, 0);
            T0 = __builtin_amdgcn_mfma_f32_16x16x32_f16(aM[0][0], u0.h, T0, 0, 0, 0);
            T1 = __builtin_amdgcn_mfma_f32_16x16x32_f16(aM[1][0], u0.h, T1, 0, 0, 0);
            T2 = __builtin_amdgcn_mfma_f32_16x16x32_f16(aM[2][0], u0.h, T2, 0, 0, 0);
            T3 = __builtin_amdgcn_mfma_f32_16x16x32_f16(aM[3][0], u0.h, T3, 0, 0, 0);
            T0 = __builtin_amdgcn_mfma_f32_16x16x32_f16(aM[0][1], u1.h, T0, 0, 0, 0);
            T1 = __builtin_amdgcn_mfma_f32_16x16x32_f16(aM[1][1], u1.h, T1, 0, 0, 0);
            T2 = __builtin_amdgcn_mfma_f32_16x16x32_f16(aM[2][1], u1.h, T2, 0, 0, 0);
            T3 = __builtin_amdgcn_mfma_f32_16x16x32_f16(aM[3][1], u1.h, T3, 0, 0, 0);

            // write gates_g(t): cell (hid 16w+4j+quad, batch col), cols 0-7
            if (col < 8) {
                char* gb = lds + GOFF + g * GSZ;
                *(f32x4*)(gb + (((w * 16 + 0 + quad) * 8 + col) * 16)) = T0;
                *(f32x4*)(gb + (((w * 16 + 4 + quad) * 8 + col) * 16)) = T1;
                *(f32x4*)(gb + (((w * 16 + 8 + quad) * 8 + col) * 16)) = T2;
                *(f32x4*)(gb + (((w * 16 + 12 + quad) * 8 + col) * 16)) = T3;
            }
            asm volatile("s_waitcnt lgkmcnt(0)" ::: "memory");
            if (lane == 0) vg[w] = u + 1;
        }

        // ---- epilogue: h_T = Whr @ d(511) (both groups final) ----
        poll4(vd, 2 * T_STEPS);
        half8 aP[2];
        const int prow = w * 16 + col;
#pragma unroll
        for (int ch = 0; ch < 2; ++ch)
#pragma unroll
            for (int jj = 0; jj < 8; ++jj) {
                const int k = ch * 32 + quad * 8 + jj;
                aP[ch][jj] = (_Float16)((prow < NPROJ) ? Whr[prow * HID + k] : 0.0f);
            }
        half8 bd0, bd1;
        {
            const char* p0 = dl + col * ROWB + quad * 16;
            union { ull q[2]; half8 h; } u0, u1;
            u0.q[0] = *(const ull*)(p0);      u0.q[1] = *(const ull*)(p0 + 8);
            u1.q[0] = *(const ull*)(p0 + 64); u1.q[1] = *(const ull*)(p0 + 72);
            bd0 = u0.h; bd1 = u1.h;
        }
        f32x4 hf = {0.f, 0.f, 0.f, 0.f};
        hf = __builtin_amdgcn_mfma_f32_16x16x32_f16(aP[0], bd0, hf, 0, 0, 0);
        hf = __builtin_amdgcn_mfma_f32_16x16x32_f16(aP[1], bd1, hf, 0, 0, 0);
        const size_t bg = (size_t)blockIdx.x * NBATCH + col;
        float* o = out + bg * NPROJ;
        const int pb = w * 16 + quad * 4;
#pragma unroll
        for (int r = 0; r < 4; ++r) {
            const int p = pb + r;
            if (p < NPROJ) o[p] = hf[r];
        }
    } else {
        // ===================== CONSUMER (hid slice [16c,16c+16)) ==========
        const int c  = wave - 4;
        const int b  = col & 7;
        const int hp = col >> 3;
        const int h0 = c * 16 + quad + 4 * hp;    // cells: hid = h0, h0+8
        float cA0 = 0.f, cA1 = 0.f, cB0 = 0.f, cB1 = 0.f;   // c' = 2L*c

        // one half-step: read gates_g(t), trans 2 cells, write d_g(t), flag
        auto CHALF = [&](int u, int g, float& cc0, float& cc1) {
            poll4(vg, u + 1);   // gates_g(t) written; d_g(t-1) fully read
            const char* gb = lds + GOFF + g * GSZ;
            const f32x4 A0 = *(const f32x4*)(gb + ((h0 * 8 + b) * 16));
            const f32x4 A1 = *(const f32x4*)(gb + (((h0 + 8) * 8 + b) * 16));
            char* drow = dl + (g * 8 + b) * ROWB;
            {   // cell 0: [i,f,g,o] = A0
                const float iv = rcp_f(1.0f + exp2_f(-A0[0]));
                const float fv = rcp_f(1.0f + exp2_f(-A0[1]));
                const float gs = fmaf(-4.0f * LOG2E,
                                      rcp_f(1.0f + exp2_f(A0[2])), 2.0f * LOG2E);
                const float ov = rcp_f(1.0f + exp2_f(-A0[3]));
                const float cn = fmaf(fv, cc0, iv * gs);
                cc0 = cn;
                const float th = fmaf(-2.0f, rcp_f(1.0f + exp2_f(cn)), 1.0f);
                *(_Float16*)(drow + h0 * 2) = (_Float16)(ov * th);      // RTNE
            }
            {   // cell 1
                const float iv = rcp_f(1.0f + exp2_f(-A1[0]));
                const float fv = rcp_f(1.0f + exp2_f(-A1[1]));
                const float gs = fmaf(-4.0f * LOG2E,
                                      rcp_f(1.0f + exp2_f(A1[2])), 2.0f * LOG2E);
                const float ov = rcp_f(1.0f + exp2_f(-A1[3]));
                const float cn = fmaf(fv, cc1, iv * gs);
                cc1 = cn;
                const float th = fmaf(-2.0f, rcp_f(1.0f + exp2_f(cn)), 1.0f);
                *(_Float16*)(drow + (h0 + 8) * 2) = (_Float16)(ov * th); // RTNE
            }
            asm volatile("s_waitcnt lgkmcnt(0)" ::: "memory");
            if (lane == 0) vd[c] = u + 1;
        };

#pragma unroll 1
        for (int tt = 0; tt < T_STEPS; ++tt) {
            CHALF(2 * tt,     0, cA0, cA1);   // group A
            CHALF(2 * tt + 1, 1, cB0, cB1);   // group B
        }
    }
}

extern "C" void kernel_launch(void* const* d_in, const int* in_sizes, int n_in,
                              void* d_out, int out_size, void* d_ws, size_t ws_size,
                              hipStream_t stream) {
    const float* x   = (const float*)d_in[0];
    const float* Wih = (const float*)d_in[1];
    const float* Whh = (const float*)d_in[2];
    const float* bih = (const float*)d_in[3];
    const float* bhh = (const float*)d_in[4];
    const float* Whr = (const float*)d_in[5];
    float* out = (float*)d_out;

    dim3 grid(4096 / NBATCH);   // 256 blocks, 1 per CU (LDS-limited anyway)
    dim3 block(512);            // 8 waves: 4 producers + 4 consumers
    lstmp_kernel<<<grid, block, 0, stream>>>(x, Wih, Whh, bih, bhh, Whr, out);
}

// Round 9
// 303.432 us; speedup vs baseline: 2.2062x; 2.2062x over previous
//
#include <hip/hip_runtime.h>

// LSTMP via MFMA, fp32 I/O, f16 compute, fp32 accumulate.
// B=4096, T=512, IN=4, HID=64, PROJ=52. Grid 256 x 512thr (8 waves, 2/SIMD),
// 16 batch/block.
//
// Round-21 = Round-13 (best verified: 253us) + READ-WINDOW FILL.
// Structural ledger: R15 blocks / R19 phase-split / R20 producer-consumer all
// cost MORE sync overhead than the ~500 cyc/step correlated idle they chase.
// Keep the single-barrier lockstep loop; surgically fill its idle:
//  1. x(t+1) PREFETCHED to registers during step t (1 ds_read_b64, latency
//     hidden by the whole step) -> bx assembly is pure VALU.
//  2. xb-MFMAs moved POST-barrier, register-fed: they issue inside the
//     d-ds_read wait window (no lgkm dependence), filling ~100 of the
//     ~120-cycle read stall. Per-output accumulate order unchanged:
//     z-seed -> xb -> M0(bd0) -> M1(bd1)  == R13 exactly.
// Gate-packed tiles as R13: P0 rows [i(h),f(h)] interleaved, P1 [g,o];
// lane's a0 = [i(c0),f(c0),i(c1),f(c1)], a1 = [g,o,g,o]; 2 cells/lane,
// contiguous-hid d cells -> one b32 d-write. Scales s0/s1, f16 RTNE,
// fp32 gates identical to R12/R13 -> absmax exactly 9.765625e-4.
//   gates = (Whh@Whr)@d + [Wih|b]@[x;1]   (M precomputed per block, fp32)
// x staged to LDS as f16 once; d double-buffered (136B rows);
// ONE barrier/step; h only in epilogue (Whr@d_T, waves 0-3).
// log2e folded (i,f,o rows xL; g rows x2L; c' = 2L*c).

#define T_STEPS 512
#define HID 64
#define NPROJ 52
#define NBATCH 16
#define ROWB 136
#define DBYTES (NBATCH * ROWB)     // 2176 B per d buffer
#define XBYTES (T_STEPS * 128)     // 65536 B: x_lds[t][b] 8B cells (4 x f16)
#define LOG2E 1.44269504088896340736f

typedef _Float16 half8 __attribute__((ext_vector_type(8)));
typedef float f32x4 __attribute__((ext_vector_type(4)));
typedef unsigned long long ull;

__device__ __forceinline__ float exp2_f(float x) {
#if __has_builtin(__builtin_amdgcn_exp2f)
    return __builtin_amdgcn_exp2f(x);
#else
    return exp2f(x);
#endif
}
__device__ __forceinline__ float rcp_f(float x) {
    return __builtin_amdgcn_rcpf(x);
}

__global__ __launch_bounds__(512, 2)
void lstmp_kernel(const float* __restrict__ x,      // [4096][512][4]
                  const float* __restrict__ Wih,    // [256][4]
                  const float* __restrict__ Whh,    // [256][52]
                  const float* __restrict__ bih,    // [256]
                  const float* __restrict__ bhh,    // [256]
                  const float* __restrict__ Whr,    // [52][64]
                  float* __restrict__ out)          // [4096][52]
{
    __shared__ char lds[XBYTES + 2 * DBYTES];
    char* xl = lds;                 // x_lds: [t][b] 8B cells
    char* dl = lds + XBYTES;        // double-buffered d, [16 batch][136B]

    const int tid  = threadIdx.x;
    const int lane = tid & 63;
    const int wave = tid >> 6;           // 0..7, owns hid block [8w, 8w+8)
    const int quad = lane >> 4;
    const int col  = lane & 15;          // batch (B/C col), tile row (A)

    // ---- zero d buffers (t=0 reads buffer 0 as d(-1)=0) ----
    {
        unsigned* p = (unsigned*)dl;
        for (int i = tid; i < (int)(2 * DBYTES / 4); i += 512) p[i] = 0u;
    }

    // ---- stage x -> LDS as f16 (one-time; coalesced global reads) ----
    {
        const float4* xg = (const float4*)x + (size_t)blockIdx.x * NBATCH * T_STEPS;
        for (int i = tid; i < NBATCH * T_STEPS; i += 512) {
            const int b = i >> 9;          // global layout is b-major
            const int t = i & (T_STEPS - 1);
            const float4 v = xg[i];
            union { _Float16 h[4]; ull q; } u;
            u.h[0] = (_Float16)v.x; u.h[1] = (_Float16)v.y;
            u.h[2] = (_Float16)v.z; u.h[3] = (_Float16)v.w;
            *(ull*)(xl + t * 128 + b * 8) = u.q;
        }
    }

    // ---- this lane's two A-frag rows (tile row = col, interleaved packing) --
    // tile row tr of P0 -> gate (tr&1 ? f : i), hid = 8*wave + (tr>>1)
    // tile row tr of P1 -> gate (tr&1 ? o : g), hid = 8*wave + (tr>>1)
    const int hw    = wave * 8 + (col >> 1);
    const int gsel  = col & 1;
    const int rowP0 = gsel * HID + hw;          // gate 0 (i) / 1 (f)
    const int rowP1 = (2 + gsel) * HID + hw;    // gate 2 (g) / 3 (o)

    // ---- one-time: M = Whh @ Whr for the two packed rows (fp32) ----
    float macc[2][16];
#pragma unroll
    for (int g = 0; g < 2; ++g)
#pragma unroll
        for (int kk = 0; kk < 16; ++kk) macc[g][kk] = 0.0f;

    for (int p = 0; p < NPROJ; ++p) {
        const float w0 = Whh[rowP0 * NPROJ + p];
        const float w1 = Whh[rowP1 * NPROJ + p];
        const float* wr = Whr + p * HID + quad * 8;
        const float4 r0 = *(const float4*)(wr);
        const float4 r1 = *(const float4*)(wr + 4);
        const float4 r2 = *(const float4*)(wr + 32);
        const float4 r3 = *(const float4*)(wr + 36);
        const float rk[16] = {r0.x, r0.y, r0.z, r0.w, r1.x, r1.y, r1.z, r1.w,
                              r2.x, r2.y, r2.z, r2.w, r3.x, r3.y, r3.z, r3.w};
#pragma unroll
        for (int kk = 0; kk < 16; ++kk) {
            macc[0][kk] = fmaf(w0, rk[kk], macc[0][kk]);
            macc[1][kk] = fmaf(w1, rk[kk], macc[1][kk]);
        }
    }

    // ---- fold log2e, convert to f16 A-frags ----
    const float s0 = LOG2E;                                  // i and f rows
    const float s1 = (gsel == 0) ? (2.0f * LOG2E) : LOG2E;   // g rows x2L, o xL
    half8 aM0[2], aM1[2];   // M-part, K=64 (2 chunks)
    half8 aXB0, aXB1;       // [Wih | bias] part, K=32 (quad0: k<4 = x, k==4 = 1)
#pragma unroll
    for (int ch = 0; ch < 2; ++ch)
#pragma unroll
        for (int j = 0; j < 8; ++j) {
            aM0[ch][j] = (_Float16)(macc[0][ch * 8 + j] * s0);
            aM1[ch][j] = (_Float16)(macc[1][ch * 8 + j] * s1);
        }
#pragma unroll
    for (int j = 0; j < 8; ++j) {
        const int k = quad * 8 + j;
        float v0 = 0.0f, v1 = 0.0f;
        if (k < 4) {
            v0 = Wih[rowP0 * 4 + k];
            v1 = Wih[rowP1 * 4 + k];
        } else if (k == 4) {
            v0 = bih[rowP0] + bhh[rowP0];
            v1 = bih[rowP1] + bhh[rowP1];
        }
        aXB0[j] = (_Float16)(v0 * s0);
        aXB1[j] = (_Float16)(v1 * s1);
    }

    float cacc[2] = {0.0f, 0.0f};        // c' = 2L*c; cells hid = 8w+2q+{0,1}

    const int dwoff  = col * ROWB + wave * 16 + quad * 4;  // d write (b32, 2 f16)
    const int drbase = col * ROWB + quad * 16;             // d read base (+64 ch1)
    const char* xrd  = xl + col * 8;                       // + t*128 per step

    __syncthreads();   // staging + zeros visible

    // ---- prologue: x(0) into registers ----
    ull xq_cur = (quad == 0) ? *(const ull*)(xrd + 0 * 128) : 0ull;

#pragma unroll 1
    for (int t = 0; t < T_STEPS; ++t) {
        const char* rbuf = dl + (t & 1) * DBYTES;
        char* wbuf = dl + ((t + 1) & 1) * DBYTES;

        // ---- 1. issue LDS reads: d(t-1) B-frags + x(t+1) prefetch ----
        half8 bd0, bd1;
        {
            const char* p0 = rbuf + drbase;
            union { ull q[2]; half8 h; } u0, u1;
            u0.q[0] = *(const ull*)(p0);
            u0.q[1] = *(const ull*)(p0 + 8);
            u1.q[0] = *(const ull*)(p0 + 64);
            u1.q[1] = *(const ull*)(p0 + 72);
            bd0 = u0.h; bd1 = u1.h;
        }
        const int tn = (t + 1 < T_STEPS) ? (t + 1) : (T_STEPS - 1);
        ull xq_next = (quad == 0) ? *(const ull*)(xrd + tn * 128) : 0ull;

        // ---- 2. bx from registers; xb-MFMAs fill the d-read wait window ----
        union { ull q; _Float16 h[4]; } xu;
        xu.q = xq_cur;
        half8 bx;
#pragma unroll
        for (int j = 0; j < 8; ++j) bx[j] = (_Float16)0.0f;
        if (quad == 0) {
            bx[0] = xu.h[0]; bx[1] = xu.h[1]; bx[2] = xu.h[2]; bx[3] = xu.h[3];
            bx[4] = (_Float16)1.0f;
        }
        const f32x4 z = {0.f, 0.f, 0.f, 0.f};
        // accumulate order per output: xb, M0(bd0), M1(bd1) — exactly R13.
        f32x4 a0 = __builtin_amdgcn_mfma_f32_16x16x32_f16(aXB0, bx, z, 0, 0, 0);
        f32x4 a1 = __builtin_amdgcn_mfma_f32_16x16x32_f16(aXB1, bx, z, 0, 0, 0);

        a0 = __builtin_amdgcn_mfma_f32_16x16x32_f16(aM0[0], bd0, a0, 0, 0, 0);
        a1 = __builtin_amdgcn_mfma_f32_16x16x32_f16(aM1[0], bd0, a1, 0, 0, 0);
        a0 = __builtin_amdgcn_mfma_f32_16x16x32_f16(aM0[1], bd1, a0, 0, 0, 0);
        a1 = __builtin_amdgcn_mfma_f32_16x16x32_f16(aM1[1], bd1, a1, 0, 0, 0);

        // ---- 3. activations + cell update: 2 cells/lane, no cross-lane ----
        // a0 = [i(c0), f(c0), i(c1), f(c1)], a1 = [g(c0), o(c0), g(c1), o(c1)]
        union { _Float16 h[2]; unsigned w; } du;
#pragma unroll
        for (int u = 0; u < 2; ++u) {
            const float iv = rcp_f(1.0f + exp2_f(-a0[2 * u]));                    // sigmoid
            const float fv = rcp_f(1.0f + exp2_f(-a0[2 * u + 1]));
            const float ov = rcp_f(1.0f + exp2_f(-a1[2 * u + 1]));
            const float gs = fmaf(-4.0f * LOG2E, rcp_f(1.0f + exp2_f(a1[2 * u])),
                                  2.0f * LOG2E);                                  // 2L*tanh(g)
            const float cn = fmaf(fv, cacc[u], iv * gs);                          // c' = 2L*c
            cacc[u] = cn;
            const float th = fmaf(-2.0f, rcp_f(1.0f + exp2_f(cn)), 1.0f);         // tanh(c)
            du.h[u] = (_Float16)(ov * th);                                        // RTNE
        }
        *(unsigned*)(wbuf + dwoff) = du.w;

        __syncthreads();   // the ONLY barrier per step
        xq_cur = xq_next;
    }

    // ---- epilogue: h_T = Whr @ d(511); d(511) is in buffer 0; waves 0-3 ----
    if (wave < 4) {
        half8 aP[2];
        const int prow = wave * 16 + col;
#pragma unroll
        for (int ch = 0; ch < 2; ++ch)
#pragma unroll
            for (int j = 0; j < 8; ++j) {
                const int k = ch * 32 + quad * 8 + j;
                aP[ch][j] = (_Float16)((prow < NPROJ) ? Whr[prow * HID + k] : 0.0f);
            }

        half8 bd0, bd1;
        {
            const char* p0 = dl + 0 * DBYTES + drbase;
            union { ull q[2]; half8 h; } u0, u1;
            u0.q[0] = *(const ull*)(p0);
            u0.q[1] = *(const ull*)(p0 + 8);
            u1.q[0] = *(const ull*)(p0 + 64);
            u1.q[1] = *(const ull*)(p0 + 72);
            bd0 = u0.h; bd1 = u1.h;
        }
        f32x4 hf = {0.f, 0.f, 0.f, 0.f};
        hf = __builtin_amdgcn_mfma_f32_16x16x32_f16(aP[0], bd0, hf, 0, 0, 0);
        hf = __builtin_amdgcn_mfma_f32_16x16x32_f16(aP[1], bd1, hf, 0, 0, 0);

        // store: p = wave*16 + quad*4 + r, batch = col (wave 3: only quad 0 valid)
        const size_t bg = (size_t)blockIdx.x * NBATCH + col;
        float* o = out + bg * NPROJ;
        const int p0 = wave * 16 + quad * 4;
#pragma unroll
        for (int r = 0; r < 4; ++r) {
            const int p = p0 + r;
            if (p < NPROJ) o[p] = hf[r];
        }
    }
}

extern "C" void kernel_launch(void* const* d_in, const int* in_sizes, int n_in,
                              void* d_out, int out_size, void* d_ws, size_t ws_size,
                              hipStream_t stream) {
    const float* x   = (const float*)d_in[0];
    const float* Wih = (const float*)d_in[1];
    const float* Whh = (const float*)d_in[2];
    const float* bih = (const float*)d_in[3];
    const float* bhh = (const float*)d_in[4];
    const float* Whr = (const float*)d_in[5];
    float* out = (float*)d_out;

    dim3 grid(4096 / NBATCH);   // 256 blocks, 1 per CU
    dim3 block(512);            // 8 waves, 2 waves/SIMD
    lstmp_kernel<<<grid, block, 0, stream>>>(x, Wih, Whh, bih, bhh, Whr, out);
}

// Round 10
// 300.367 us; speedup vs baseline: 2.2287x; 1.0102x over previous
//
#include <hip/hip_runtime.h>

// LSTMP via MFMA, fp32 I/O, f16 compute, fp32 accumulate.
// B=4096, T=512, IN=4, HID=64, PROJ=52. Grid 256 x 512thr (8 waves, 2/SIMD),
// 16 batch/block.
//
// Round-22 = Round-21 base (verified 258us, absmax 2^-10) + micro-shave:
//  1. bx built via 3 dword-cndmasks (quad0 ? {xq.lo, xq.hi, 0x3C00} : 0)
//     instead of 8 half zero-init + 5 fills — identical bits, ~8 fewer ops.
//  2. d-write split into 2 x b16, each issued right after its cell's trans
//     chain — cell0's write drains ~80cyc earlier, shrinking barrier tail.
//  3. t+1 x-prefetch unclamped (t=511 reads discarded bytes from d region —
//     in-bounds LDS, value never consumed).
//  4. asymmetric s_setprio(1) on odd waves — persistent per-wave priority
//     skew to break the natural lockstep of the two same-code waves/SIMD
//     (distinct from uniform MFMA-cluster setprio, which is known-null).
// Structural ledger (all measured worse/null): more waves (R13), sibling
// blocks (R15), dataflow repack (R16), 2-barrier phase split (R18/R19),
// producer/consumer waves (R20), read-window fill (R21). Step ~1210cyc =
// issue ~605 + barrier ~220 + serial chains ~350. Barrier is forced: the
// hid-split d-exchange is the only MFMA C-layout spreading trans across
// all 64 lanes.
// Numerics identical to R13/R21: per-output accumulate order z-seed -> xb
// -> M0(bd0) -> M1(bd1); scales s0/s1; f16 RTNE d -> absmax exactly
// 9.765625e-4.
//   gates = (Whh@Whr)@d + [Wih|b]@[x;1]   (M precomputed per block, fp32)
// x staged to LDS as f16 once; d double-buffered (136B rows);
// ONE barrier/step; h only in epilogue (Whr@d_T, waves 0-3).
// log2e folded (i,f,o rows xL; g rows x2L; c' = 2L*c).

#define T_STEPS 512
#define HID 64
#define NPROJ 52
#define NBATCH 16
#define ROWB 136
#define DBYTES (NBATCH * ROWB)     // 2176 B per d buffer
#define XBYTES (T_STEPS * 128)     // 65536 B: x_lds[t][b] 8B cells (4 x f16)
#define LOG2E 1.44269504088896340736f

typedef _Float16 half8 __attribute__((ext_vector_type(8)));
typedef float f32x4 __attribute__((ext_vector_type(4)));
typedef unsigned long long ull;

__device__ __forceinline__ float exp2_f(float x) {
#if __has_builtin(__builtin_amdgcn_exp2f)
    return __builtin_amdgcn_exp2f(x);
#else
    return exp2f(x);
#endif
}
__device__ __forceinline__ float rcp_f(float x) {
    return __builtin_amdgcn_rcpf(x);
}

__global__ __launch_bounds__(512, 2)
void lstmp_kernel(const float* __restrict__ x,      // [4096][512][4]
                  const float* __restrict__ Wih,    // [256][4]
                  const float* __restrict__ Whh,    // [256][52]
                  const float* __restrict__ bih,    // [256]
                  const float* __restrict__ bhh,    // [256]
                  const float* __restrict__ Whr,    // [52][64]
                  float* __restrict__ out)          // [4096][52]
{
    __shared__ char lds[XBYTES + 2 * DBYTES];
    char* xl = lds;                 // x_lds: [t][b] 8B cells
    char* dl = lds + XBYTES;        // double-buffered d, [16 batch][136B]

    const int tid  = threadIdx.x;
    const int lane = tid & 63;
    const int wave = tid >> 6;           // 0..7, owns hid block [8w, 8w+8)
    const int quad = lane >> 4;
    const int col  = lane & 15;          // batch (B/C col), tile row (A)
    const bool q0  = (quad == 0);

    // ---- zero d buffers (t=0 reads buffer 0 as d(-1)=0) ----
    {
        unsigned* p = (unsigned*)dl;
        for (int i = tid; i < (int)(2 * DBYTES / 4); i += 512) p[i] = 0u;
    }

    // ---- stage x -> LDS as f16 (one-time; coalesced global reads) ----
    {
        const float4* xg = (const float4*)x + (size_t)blockIdx.x * NBATCH * T_STEPS;
        for (int i = tid; i < NBATCH * T_STEPS; i += 512) {
            const int b = i >> 9;          // global layout is b-major
            const int t = i & (T_STEPS - 1);
            const float4 v = xg[i];
            union { _Float16 h[4]; ull q; } u;
            u.h[0] = (_Float16)v.x; u.h[1] = (_Float16)v.y;
            u.h[2] = (_Float16)v.z; u.h[3] = (_Float16)v.w;
            *(ull*)(xl + t * 128 + b * 8) = u.q;
        }
    }

    // ---- this lane's two A-frag rows (tile row = col, interleaved packing) --
    // tile row tr of P0 -> gate (tr&1 ? f : i), hid = 8*wave + (tr>>1)
    // tile row tr of P1 -> gate (tr&1 ? o : g), hid = 8*wave + (tr>>1)
    const int hw    = wave * 8 + (col >> 1);
    const int gsel  = col & 1;
    const int rowP0 = gsel * HID + hw;          // gate 0 (i) / 1 (f)
    const int rowP1 = (2 + gsel) * HID + hw;    // gate 2 (g) / 3 (o)

    // ---- one-time: M = Whh @ Whr for the two packed rows (fp32) ----
    float macc[2][16];
#pragma unroll
    for (int g = 0; g < 2; ++g)
#pragma unroll
        for (int kk = 0; kk < 16; ++kk) macc[g][kk] = 0.0f;

    for (int p = 0; p < NPROJ; ++p) {
        const float w0 = Whh[rowP0 * NPROJ + p];
        const float w1 = Whh[rowP1 * NPROJ + p];
        const float* wr = Whr + p * HID + quad * 8;
        const float4 r0 = *(const float4*)(wr);
        const float4 r1 = *(const float4*)(wr + 4);
        const float4 r2 = *(const float4*)(wr + 32);
        const float4 r3 = *(const float4*)(wr + 36);
        const float rk[16] = {r0.x, r0.y, r0.z, r0.w, r1.x, r1.y, r1.z, r1.w,
                              r2.x, r2.y, r2.z, r2.w, r3.x, r3.y, r3.z, r3.w};
#pragma unroll
        for (int kk = 0; kk < 16; ++kk) {
            macc[0][kk] = fmaf(w0, rk[kk], macc[0][kk]);
            macc[1][kk] = fmaf(w1, rk[kk], macc[1][kk]);
        }
    }

    // ---- fold log2e, convert to f16 A-frags ----
    const float s0 = LOG2E;                                  // i and f rows
    const float s1 = (gsel == 0) ? (2.0f * LOG2E) : LOG2E;   // g rows x2L, o xL
    half8 aM0[2], aM1[2];   // M-part, K=64 (2 chunks)
    half8 aXB0, aXB1;       // [Wih | bias] part, K=32 (quad0: k<4 = x, k==4 = 1)
#pragma unroll
    for (int ch = 0; ch < 2; ++ch)
#pragma unroll
        for (int j = 0; j < 8; ++j) {
            aM0[ch][j] = (_Float16)(macc[0][ch * 8 + j] * s0);
            aM1[ch][j] = (_Float16)(macc[1][ch * 8 + j] * s1);
        }
#pragma unroll
    for (int j = 0; j < 8; ++j) {
        const int k = quad * 8 + j;
        float v0 = 0.0f, v1 = 0.0f;
        if (k < 4) {
            v0 = Wih[rowP0 * 4 + k];
            v1 = Wih[rowP1 * 4 + k];
        } else if (k == 4) {
            v0 = bih[rowP0] + bhh[rowP0];
            v1 = bih[rowP1] + bhh[rowP1];
        }
        aXB0[j] = (_Float16)(v0 * s0);
        aXB1[j] = (_Float16)(v1 * s1);
    }

    float cacc[2] = {0.0f, 0.0f};        // c' = 2L*c; cells hid = 8w+2q+{0,1}

    const int dwoff  = col * ROWB + wave * 16 + quad * 4;  // d write base (2 f16)
    const int drbase = col * ROWB + quad * 16;             // d read base (+64 ch1)
    const char* xrd  = xl + col * 8;                       // + t*128 per step

    __syncthreads();   // staging + zeros visible

    // asymmetric wave priority: persistent skew to break 2-wave lockstep
    if (wave & 1) __builtin_amdgcn_s_setprio(1);

    // ---- prologue: x(0) into registers ----
    ull xq_cur = q0 ? *(const ull*)(xrd + 0 * 128) : 0ull;

#pragma unroll 1
    for (int t = 0; t < T_STEPS; ++t) {
        const char* rbuf = dl + (t & 1) * DBYTES;
        char* wbuf = dl + ((t + 1) & 1) * DBYTES;

        // ---- 1. issue LDS reads: d(t-1) B-frags + x(t+1) prefetch ----
        half8 bd0, bd1;
        {
            const char* p0 = rbuf + drbase;
            union { ull q[2]; half8 h; } u0, u1;
            u0.q[0] = *(const ull*)(p0);
            u0.q[1] = *(const ull*)(p0 + 8);
            u1.q[0] = *(const ull*)(p0 + 64);
            u1.q[1] = *(const ull*)(p0 + 72);
            bd0 = u0.h; bd1 = u1.h;
        }
        // unclamped: at t=511 this reads discarded bytes from the d region
        // (in-bounds LDS, value never consumed).
        ull xq_next = q0 ? *(const ull*)(xrd + (t + 1) * 128) : 0ull;

        // ---- 2. bx from registers (3 cndmask dwords — identical bits) ----
        union { ull q; unsigned d[2]; } xc;
        xc.q = xq_cur;
        union { unsigned d[4]; half8 h; } bxu;
        bxu.d[0] = q0 ? xc.d[0] : 0u;
        bxu.d[1] = q0 ? xc.d[1] : 0u;
        bxu.d[2] = q0 ? 0x00003C00u : 0u;   // bx[4] = 1.0h
        bxu.d[3] = 0u;
        const half8 bx = bxu.h;

        const f32x4 z = {0.f, 0.f, 0.f, 0.f};
        // accumulate order per output: xb, M0(bd0), M1(bd1) — exactly R13.
        f32x4 a0 = __builtin_amdgcn_mfma_f32_16x16x32_f16(aXB0, bx, z, 0, 0, 0);
        f32x4 a1 = __builtin_amdgcn_mfma_f32_16x16x32_f16(aXB1, bx, z, 0, 0, 0);

        a0 = __builtin_amdgcn_mfma_f32_16x16x32_f16(aM0[0], bd0, a0, 0, 0, 0);
        a1 = __builtin_amdgcn_mfma_f32_16x16x32_f16(aM1[0], bd0, a1, 0, 0, 0);
        a0 = __builtin_amdgcn_mfma_f32_16x16x32_f16(aM0[1], bd1, a0, 0, 0, 0);
        a1 = __builtin_amdgcn_mfma_f32_16x16x32_f16(aM1[1], bd1, a1, 0, 0, 0);

        // ---- 3. activations; each cell's d written right after its chain ----
        // a0 = [i(c0), f(c0), i(c1), f(c1)], a1 = [g(c0), o(c0), g(c1), o(c1)]
#pragma unroll
        for (int u = 0; u < 2; ++u) {
            const float iv = rcp_f(1.0f + exp2_f(-a0[2 * u]));                    // sigmoid
            const float fv = rcp_f(1.0f + exp2_f(-a0[2 * u + 1]));
            const float ov = rcp_f(1.0f + exp2_f(-a1[2 * u + 1]));
            const float gs = fmaf(-4.0f * LOG2E, rcp_f(1.0f + exp2_f(a1[2 * u])),
                                  2.0f * LOG2E);                                  // 2L*tanh(g)
            const float cn = fmaf(fv, cacc[u], iv * gs);                          // c' = 2L*c
            cacc[u] = cn;
            const float th = fmaf(-2.0f, rcp_f(1.0f + exp2_f(cn)), 1.0f);         // tanh(c)
            *(_Float16*)(wbuf + dwoff + u * 2) = (_Float16)(ov * th);             // RTNE
        }

        __syncthreads();   // the ONLY barrier per step
        xq_cur = xq_next;
    }

    // ---- epilogue: h_T = Whr @ d(511); d(511) is in buffer 0; waves 0-3 ----
    if (wave < 4) {
        half8 aP[2];
        const int prow = wave * 16 + col;
#pragma unroll
        for (int ch = 0; ch < 2; ++ch)
#pragma unroll
            for (int j = 0; j < 8; ++j) {
                const int k = ch * 32 + quad * 8 + j;
                aP[ch][j] = (_Float16)((prow < NPROJ) ? Whr[prow * HID + k] : 0.0f);
            }

        half8 bd0, bd1;
        {
            const char* p0 = dl + 0 * DBYTES + drbase;
            union { ull q[2]; half8 h; } u0, u1;
            u0.q[0] = *(const ull*)(p0);
            u0.q[1] = *(const ull*)(p0 + 8);
            u1.q[0] = *(const ull*)(p0 + 64);
            u1.q[1] = *(const ull*)(p0 + 72);
            bd0 = u0.h; bd1 = u1.h;
        }
        f32x4 hf = {0.f, 0.f, 0.f, 0.f};
        hf = __builtin_amdgcn_mfma_f32_16x16x32_f16(aP[0], bd0, hf, 0, 0, 0);
        hf = __builtin_amdgcn_mfma_f32_16x16x32_f16(aP[1], bd1, hf, 0, 0, 0);

        // store: p = wave*16 + quad*4 + r, batch = col (wave 3: only quad 0 valid)
        const size_t bg = (size_t)blockIdx.x * NBATCH + col;
        float* o = out + bg * NPROJ;
        const int p0 = wave * 16 + quad * 4;
#pragma unroll
        for (int r = 0; r < 4; ++r) {
            const int p = p0 + r;
            if (p < NPROJ) o[p] = hf[r];
        }
    }
}

extern "C" void kernel_launch(void* const* d_in, const int* in_sizes, int n_in,
                              void* d_out, int out_size, void* d_ws, size_t ws_size,
                              hipStream_t stream) {
    const float* x   = (const float*)d_in[0];
    const float* Wih = (const float*)d_in[1];
    const float* Whh = (const float*)d_in[2];
    const float* bih = (const float*)d_in[3];
    const float* bhh = (const float*)d_in[4];
    const float* Whr = (const float*)d_in[5];
    float* out = (float*)d_out;

    dim3 grid(4096 / NBATCH);   // 256 blocks, 1 per CU
    dim3 block(512);            // 8 waves, 2 waves/SIMD
    lstmp_kernel<<<grid, block, 0, stream>>>(x, Wih, Whh, bih, bhh, Whr, out);
}